// Round 10
// baseline (239076.855 us; speedup 1.0000x reference)
//
#include <hip/hip_runtime.h>

typedef __attribute__((ext_vector_type(8))) short short8;
typedef __attribute__((ext_vector_type(4))) float f32x4;
typedef __attribute__((ext_vector_type(4))) unsigned uint32x4;

#define SEQ 4096
#define HID 2048
#define G4  8192
#define NBLK 256

static __device__ __forceinline__ ushort f2bf(float f) {
    unsigned u = __float_as_uint(f);
    u = (u + 0x7fffu + ((u >> 16) & 1u)) >> 16;   // RNE
    return (ushort)u;
}
static __device__ __forceinline__ float bf_lo(unsigned x) { return __uint_as_float(x << 16); }
static __device__ __forceinline__ float bf_hi(unsigned x) { return __uint_as_float(x & 0xffff0000u); }

// Fire-and-forget publish of one {f32 h (lo), u32 tag (hi)} u64 at the device
// coherence point. 8 lanes of one wave -> ONE instruction, one 64 B line.
static __device__ __forceinline__ void atomic_pub_u64(unsigned long long* p,
                                                      unsigned long long v) {
    unsigned long long ap = (unsigned long long)p;
    asm volatile("global_atomic_swap_x2 %0, %1, off" :: "v"(ap), "v"(v) : "memory");
}

// Coherent READ of 4 u64 slots through the L3 atomic pipe: returning
// atomic-add of 0 (semantic no-op on data, sc0 = return old value).
// 4 atomics pipelined under one vmcnt -> poll period ~ one atomic RTT.
static __device__ __forceinline__ void atomic_poll4(const unsigned long long* p,
        unsigned long long& a0, unsigned long long& a1,
        unsigned long long& a2, unsigned long long& a3) {
    unsigned long long ap = (unsigned long long)p;
    asm volatile(
        "global_atomic_add_x2 %0, %4, %5, off sc0\n\t"
        "global_atomic_add_x2 %1, %4, %5, off offset:8 sc0\n\t"
        "global_atomic_add_x2 %2, %4, %5, off offset:16 sc0\n\t"
        "global_atomic_add_x2 %3, %4, %5, off offset:24 sc0\n\t"
        "s_waitcnt vmcnt(0)"
        : "=&v"(a0), "=&v"(a1), "=&v"(a2), "=&v"(a3)
        : "v"(ap), "v"(0ull) : "memory");
}

// h_lds address map: +4 floats pad per 32 floats -> reads <=2-way bank aliased
static __device__ __forceinline__ int hmap(int col) { return col + ((col >> 5) << 2); }

static __device__ __forceinline__ float fsigmoid(float x) {
    return 1.0f / (1.0f + __expf(-x));
}
static __device__ __forceinline__ float ftanh(float x) {
    return 1.0f - 2.0f / (__expf(2.0f * x) + 1.0f);
}

// ---------------- f32 -> bf16 conversion (vectorized, 4 elems/thread) ----------
__global__ void __launch_bounds__(256) k_f32_to_bf16(const float* __restrict__ in,
                                                     ushort* __restrict__ out, int n4) {
    int i = blockIdx.x * blockDim.x + threadIdx.x;
    if (i < n4) {
        float4 v = ((const float4*)in)[i];
        ushort4 o;
        o.x = f2bf(v.x); o.y = f2bf(v.y); o.z = f2bf(v.z); o.w = f2bf(v.w);
        ((ushort4*)out)[i] = o;
    }
}

// ---------------- xg = x @ W_ih^T + (b_ih + b_hh), bf16 MFMA, 128x128 tile ------
__global__ void __launch_bounds__(256) k_gemm_xg(
    const ushort* __restrict__ A, const ushort* __restrict__ B,
    const float* __restrict__ bih, const float* __restrict__ bhh,
    float* __restrict__ C)
{
    __shared__ ushort Asm[128 * 40];
    __shared__ ushort Bsm[128 * 40];
    const int tid = threadIdx.x;
    const int brow = blockIdx.y * 128;
    const int bcol = blockIdx.x * 128;
    const int w = tid >> 6, l = tid & 63;
    const int wm = w >> 1, wn = w & 1;

    f32x4 acc[4][4] = {};

    for (int k0 = 0; k0 < 2048; k0 += 32) {
        __syncthreads();
        #pragma unroll
        for (int i = 0; i < 2; ++i) {
            int q = tid + i * 256;
            int r = q >> 2, kc = q & 3;
            *(uint4*)((char*)Asm + r * 80 + kc * 16) =
                *(const uint4*)(A + (size_t)(brow + r) * 2048 + k0 + kc * 8);
            *(uint4*)((char*)Bsm + r * 80 + kc * 16) =
                *(const uint4*)(B + (size_t)(bcol + r) * 2048 + k0 + kc * 8);
        }
        __syncthreads();

        short8 af[4], bf[4];
        #pragma unroll
        for (int m = 0; m < 4; ++m)
            af[m] = *(const short8*)((char*)Asm + (wm * 64 + m * 16 + (l & 15)) * 80 + (l >> 4) * 16);
        #pragma unroll
        for (int n = 0; n < 4; ++n)
            bf[n] = *(const short8*)((char*)Bsm + (wn * 64 + n * 16 + (l & 15)) * 80 + (l >> 4) * 16);

        #pragma unroll
        for (int m = 0; m < 4; ++m)
            #pragma unroll
            for (int n = 0; n < 4; ++n)
                acc[m][n] = __builtin_amdgcn_mfma_f32_16x16x32_bf16(af[m], bf[n], acc[m][n], 0, 0, 0);
    }

    const int lr = (l >> 4) * 4, lc = l & 15;
    #pragma unroll
    for (int m = 0; m < 4; ++m)
        #pragma unroll
        for (int n = 0; n < 4; ++n) {
            int col = bcol + wn * 64 + n * 16 + lc;
            float bsum = bih[col] + bhh[col];
            #pragma unroll
            for (int r = 0; r < 4; ++r) {
                int rowg = brow + wm * 64 + m * 16 + lr + r;
                C[(size_t)rowg * 8192 + col] = acc[m][n][r] + bsum;
            }
        }
}

// ---------------- persistent cooperative LSTM recurrence ------------------------
// R9 structure with ONE change: polling goes through the L3 atomic pipe
// (returning add-0) instead of sc0sc1 loads.
//  - hslot[2][2048] u64 {f32 h, u32 tag}, parity double-buffered; step t polls
//    buf[t&1] for tag==t (race-free by the R7 induction).
//  - poll: each thread its OWN 4 slots, 4 pipelined returning atomics.
//  - dot: register-f32 W slice, wave u owns unit hbase+u, pure FMA.
//  - tail: wave 0 lanes 0-7 gates + c update + ONE coalesced swap_x2 publish.
__global__ void __launch_bounds__(512, 1) k_lstm_rec(
    const ushort* __restrict__ Whh,          // bf16 [8192][2048]
    const float* __restrict__ xg,            // [4096][8192]
    unsigned long long* __restrict__ hslot,  // [2][2048] {h,tag}, 0xFF-memset
    const float* __restrict__ Wlin,          // [2048]
    const float* __restrict__ blin,          // [1]
    float* __restrict__ out)                 // [1]
{
    extern __shared__ char smem[];
    float* h_lds = (float*)smem;                // 2304 f32 padded (9216 B)
    float* g_lds = (float*)(smem + 9216);       // 32 gate sums
    float* r_lds = (float*)(smem + 9216 + 128); // 8 f32 final-reduce scratch

    const int tid = threadIdx.x;
    const int b   = blockIdx.x;
    const int hbase = b * 8;
    const int u  = tid >> 6;        // wave id = local hidden unit
    const int g  = (tid >> 4) & 3;  // gate (torch order i,f,g,o)
    const int cc = tid & 15;        // col-chunk

    // one-time: stage + expand this thread's W row slice to f32 registers
    // row = g*2048 + hbase + u, cols cc*8 + k*128 + j (j=0..7, k=0..15)
    f32x4 wf[32];
    {
        const ushort* wr = Whh + (size_t)((g << 11) + hbase + u) * 2048 + (cc << 3);
        #pragma unroll
        for (int k = 0; k < 16; ++k) {
            uint4 wv = *(const uint4*)(wr + (k << 7));
            wf[2 * k]     = (f32x4){bf_lo(wv.x), bf_hi(wv.x), bf_lo(wv.y), bf_hi(wv.y)};
            wf[2 * k + 1] = (f32x4){bf_lo(wv.z), bf_hi(wv.z), bf_lo(wv.w), bf_hi(wv.w)};
        }
    }

    float c_reg = 0.0f;   // lives on wave 0 lanes 0-7 (unit = lane)

    // publish h_0 = 0 with tag 0 into buf[0] (one coalesced wave-instruction)
    if (tid < 8)
        atomic_pub_u64(&hslot[hbase + tid], 0ull);

    for (int t = 0; t < SEQ; ++t) {
        const unsigned long long* src = hslot + (size_t)(t & 1) * HID;
        unsigned long long*       dst = hslot + (size_t)((t + 1) & 1) * HID;

        // wave-0 xg prefetch (independent of h; plain cached loads)
        float xgv0 = 0.f, xgv1 = 0.f, xgv2 = 0.f, xgv3 = 0.f;
        if (tid < 8) {
            const float* xr = xg + (size_t)t * G4 + hbase + tid;
            xgv0 = xr[0]; xgv1 = xr[2048]; xgv2 = xr[4096]; xgv3 = xr[6144];
        }

        // poll own 4 slots of buf[t&1] through the atomic pipe until tags == t
        {
            const unsigned tgt = (unsigned)t;
            unsigned long long a0, a1, a2, a3;
            while (true) {
                atomic_poll4(src + tid * 4, a0, a1, a2, a3);
                if ((unsigned)(a0 >> 32) == tgt && (unsigned)(a1 >> 32) == tgt &&
                    (unsigned)(a2 >> 32) == tgt && (unsigned)(a3 >> 32) == tgt) break;
            }
            *(f32x4*)(h_lds + hmap(tid * 4)) =
                (f32x4){__uint_as_float((unsigned)a0), __uint_as_float((unsigned)a1),
                        __uint_as_float((unsigned)a2), __uint_as_float((unsigned)a3)};
        }
        __syncthreads();   // [A] h_t staged; all reads of buf[t&1] complete

        // dot: pure f32 FMA, W from registers, h from LDS (4 indep chains)
        float s0 = 0.f, s1 = 0.f, s2 = 0.f, s3 = 0.f;
        #pragma unroll
        for (int k = 0; k < 16; ++k) {
            int col0 = (cc << 3) + (k << 7);
            const float* hp = h_lds + hmap(col0);
            f32x4 ha = *(const f32x4*)hp;
            f32x4 hb = *(const f32x4*)(hp + 4);
            f32x4 wa = wf[2 * k], wb = wf[2 * k + 1];
            s0 += wa.x * ha.x;  s1 += wa.y * ha.y;
            s2 += wa.z * ha.z;  s3 += wa.w * ha.w;
            s0 += wb.x * hb.x;  s1 += wb.y * hb.y;
            s2 += wb.z * hb.z;  s3 += wb.w * hb.w;
        }
        float sum = (s0 + s1) + (s2 + s3);
        // reduce over the 16 cc lanes (intra-wave)
        sum += __shfl_xor(sum, 1);
        sum += __shfl_xor(sum, 2);
        sum += __shfl_xor(sum, 4);
        sum += __shfl_xor(sum, 8);
        if (cc == 0) g_lds[u * 4 + g] = sum;   // W_hh partial (xg added in tail)
        __syncthreads();   // [B] all 32 gate sums visible; LDS reads done

        // wave 0 lanes 0-7: gates, state update, ONE coalesced publish
        if (tid < 8) {
            float gi = fsigmoid(g_lds[tid * 4 + 0] + xgv0);
            float gf = fsigmoid(g_lds[tid * 4 + 1] + xgv1);
            float tg = ftanh   (g_lds[tid * 4 + 2] + xgv2);
            float go = fsigmoid(g_lds[tid * 4 + 3] + xgv3);
            c_reg = gf * c_reg + gi * tg;
            float hn = go * ftanh(c_reg);
            unsigned long long pv =
                ((unsigned long long)(unsigned)(t + 1) << 32) |
                (unsigned long long)__float_as_uint(hn);
            atomic_pub_u64(&dst[hbase + tid], pv);
        }
        // no trailing barrier: next-iter poll gates all h_lds/g_lds reuse
    }

    // final: out = sigmoid(h_SEQ . W_lin + b_lin), block 0 only
    // h_SEQ carries tag SEQ in buf[SEQ&1] = buf[0]
    if (b == 0) {
        const unsigned tgt = (unsigned)SEQ;
        unsigned long long a0, a1, a2, a3;
        while (true) {
            atomic_poll4(hslot + tid * 4, a0, a1, a2, a3);
            if ((unsigned)(a0 >> 32) == tgt && (unsigned)(a1 >> 32) == tgt &&
                (unsigned)(a2 >> 32) == tgt && (unsigned)(a3 >> 32) == tgt) break;
        }
        const float* wl = Wlin + tid * 4;
        float s = __uint_as_float((unsigned)a0) * wl[0]
                + __uint_as_float((unsigned)a1) * wl[1]
                + __uint_as_float((unsigned)a2) * wl[2]
                + __uint_as_float((unsigned)a3) * wl[3];
        #pragma unroll
        for (int o = 1; o < 64; o <<= 1) s += __shfl_xor(s, o);
        if ((tid & 63) == 0) r_lds[u] = s;
        __syncthreads();
        if (tid == 0) {
            float tot = r_lds[0] + r_lds[1] + r_lds[2] + r_lds[3]
                      + r_lds[4] + r_lds[5] + r_lds[6] + r_lds[7] + blin[0];
            out[0] = fsigmoid(tot);
        }
    }
}

extern "C" void kernel_launch(void* const* d_in, const int* in_sizes, int n_in,
                              void* d_out, int out_size, void* d_ws, size_t ws_size,
                              hipStream_t stream) {
    const float* x    = (const float*)d_in[0];   // [1][4096][2048]
    const float* Wih  = (const float*)d_in[1];   // [8192][2048]
    const float* Whh  = (const float*)d_in[2];   // [8192][2048]
    const float* bih  = (const float*)d_in[3];   // [8192]
    const float* bhh  = (const float*)d_in[4];   // [8192]
    const float* Wlin = (const float*)d_in[5];   // [1][2048]
    const float* blin = (const float*)d_in[6];   // [1]
    float* out = (float*)d_out;

    char* ws = (char*)d_ws;
    float*              xgbuf = (float*)ws;                        // 134,217,728 B
    ushort*             xbf   = (ushort*)(ws + 134217728);         //  16,777,216 B
    ushort*             wihbf = (ushort*)(ws + 150994944);         //  33,554,432 B
    ushort*             whhbf = (ushort*)(ws + 184549376);         //  33,554,432 B
    unsigned long long* hslot = (unsigned long long*)(ws + 218103808); // 32,768 B

    // f32 -> bf16 (x, W_ih, W_hh)
    k_f32_to_bf16<<<8192,  256, 0, stream>>>(x,   xbf,   2097152);
    k_f32_to_bf16<<<16384, 256, 0, stream>>>(Wih, wihbf, 4194304);
    k_f32_to_bf16<<<16384, 256, 0, stream>>>(Whh, whhbf, 4194304);

    // input GEMM: all timesteps' input-side gate preactivations
    k_gemm_xg<<<dim3(64, 32), 256, 0, stream>>>(xbf, wihbf, bih, bhh, xgbuf);

    // invalidate BOTH parity buffers every call (tags 0..SEQ never match 0xFF)
    hipMemsetAsync(hslot, 0xFF, 2 * HID * sizeof(unsigned long long), stream);

    // persistent cooperative recurrence: proven launch config (dyn LDS + attr)
    hipFuncSetAttribute((const void*)k_lstm_rec,
                        hipFuncAttributeMaxDynamicSharedMemorySize, 163840);
    void* args[] = { (void*)&whhbf, (void*)&xgbuf, (void*)&hslot,
                     (void*)&Wlin, (void*)&blin, (void*)&out };
    hipLaunchCooperativeKernel((const void*)k_lstm_rec, dim3(NBLK), dim3(512),
                               args, 139520, stream);
}

// Round 11
// 20251.295 us; speedup vs baseline: 11.8055x; 11.8055x over previous
//
#include <hip/hip_runtime.h>

typedef __attribute__((ext_vector_type(8))) short short8;
typedef __attribute__((ext_vector_type(4))) float f32x4;
typedef __attribute__((ext_vector_type(4))) unsigned uint32x4;

#define SEQ 4096
#define HID 2048
#define G4  8192
#define NBLK 256

static __device__ __forceinline__ ushort f2bf(float f) {
    unsigned u = __float_as_uint(f);
    u = (u + 0x7fffu + ((u >> 16) & 1u)) >> 16;   // RNE
    return (ushort)u;
}
static __device__ __forceinline__ float bf_lo(unsigned x) { return __uint_as_float(x << 16); }
static __device__ __forceinline__ float bf_hi(unsigned x) { return __uint_as_float(x & 0xffff0000u); }

// Fire-and-forget publish of one {f32 h (lo), u32 tag (hi)} u64 at the device
// coherence point. 8 lanes of one wave -> ONE instruction, one 64 B line.
static __device__ __forceinline__ void atomic_pub_u64(unsigned long long* p,
                                                      unsigned long long v) {
    unsigned long long ap = (unsigned long long)p;
    asm volatile("global_atomic_swap_x2 %0, %1, off" :: "v"(ap), "v"(v) : "memory");
}

// 128 B coherent read: 8 pipelined dwordx4 (sc0 sc1), ONE waitcnt.
// Covers 16 {h,tag} slots. READ path only - no RMW, no writebacks (R10 lesson).
static __device__ __forceinline__ void poll16(const unsigned long long* p,
        uint32x4& v0, uint32x4& v1, uint32x4& v2, uint32x4& v3,
        uint32x4& v4, uint32x4& v5, uint32x4& v6, uint32x4& v7) {
    unsigned long long ap = (unsigned long long)p;
    asm volatile(
        "global_load_dwordx4 %0, %8, off sc0 sc1\n\t"
        "global_load_dwordx4 %1, %8, off offset:16 sc0 sc1\n\t"
        "global_load_dwordx4 %2, %8, off offset:32 sc0 sc1\n\t"
        "global_load_dwordx4 %3, %8, off offset:48 sc0 sc1\n\t"
        "global_load_dwordx4 %4, %8, off offset:64 sc0 sc1\n\t"
        "global_load_dwordx4 %5, %8, off offset:80 sc0 sc1\n\t"
        "global_load_dwordx4 %6, %8, off offset:96 sc0 sc1\n\t"
        "global_load_dwordx4 %7, %8, off offset:112 sc0 sc1\n\t"
        "s_waitcnt vmcnt(0)"
        : "=&v"(v0), "=&v"(v1), "=&v"(v2), "=&v"(v3),
          "=&v"(v4), "=&v"(v5), "=&v"(v6), "=&v"(v7)
        : "v"(ap) : "memory");
}

// 32 B coherent read (two dwordx4, sc0 sc1), one waitcnt (final tail only).
static __device__ __forceinline__ void load_slot8(const unsigned long long* p,
                                                  uint32x4& a, uint32x4& b) {
    unsigned long long ap = (unsigned long long)p;
    asm volatile("global_load_dwordx4 %0, %2, off sc0 sc1\n\t"
                 "global_load_dwordx4 %1, %2, off offset:16 sc0 sc1\n\t"
                 "s_waitcnt vmcnt(0)"
                 : "=&v"(a), "=&v"(b) : "v"(ap) : "memory");
}

// h_lds address map: +4 floats pad per 32 floats -> reads <=2-way bank aliased
static __device__ __forceinline__ int hmap(int col) { return col + ((col >> 5) << 2); }

static __device__ __forceinline__ float fsigmoid(float x) {
    return 1.0f / (1.0f + __expf(-x));
}
static __device__ __forceinline__ float ftanh(float x) {
    return 1.0f - 2.0f / (__expf(2.0f * x) + 1.0f);
}

// ---------------- f32 -> bf16 conversion (vectorized, 4 elems/thread) ----------
__global__ void __launch_bounds__(256) k_f32_to_bf16(const float* __restrict__ in,
                                                     ushort* __restrict__ out, int n4) {
    int i = blockIdx.x * blockDim.x + threadIdx.x;
    if (i < n4) {
        float4 v = ((const float4*)in)[i];
        ushort4 o;
        o.x = f2bf(v.x); o.y = f2bf(v.y); o.z = f2bf(v.z); o.w = f2bf(v.w);
        ((ushort4*)out)[i] = o;
    }
}

// ---------------- xg = x @ W_ih^T + (b_ih + b_hh), bf16 MFMA, 128x128 tile ------
__global__ void __launch_bounds__(256) k_gemm_xg(
    const ushort* __restrict__ A, const ushort* __restrict__ B,
    const float* __restrict__ bih, const float* __restrict__ bhh,
    float* __restrict__ C)
{
    __shared__ ushort Asm[128 * 40];
    __shared__ ushort Bsm[128 * 40];
    const int tid = threadIdx.x;
    const int brow = blockIdx.y * 128;
    const int bcol = blockIdx.x * 128;
    const int w = tid >> 6, l = tid & 63;
    const int wm = w >> 1, wn = w & 1;

    f32x4 acc[4][4] = {};

    for (int k0 = 0; k0 < 2048; k0 += 32) {
        __syncthreads();
        #pragma unroll
        for (int i = 0; i < 2; ++i) {
            int q = tid + i * 256;
            int r = q >> 2, kc = q & 3;
            *(uint4*)((char*)Asm + r * 80 + kc * 16) =
                *(const uint4*)(A + (size_t)(brow + r) * 2048 + k0 + kc * 8);
            *(uint4*)((char*)Bsm + r * 80 + kc * 16) =
                *(const uint4*)(B + (size_t)(bcol + r) * 2048 + k0 + kc * 8);
        }
        __syncthreads();

        short8 af[4], bf[4];
        #pragma unroll
        for (int m = 0; m < 4; ++m)
            af[m] = *(const short8*)((char*)Asm + (wm * 64 + m * 16 + (l & 15)) * 80 + (l >> 4) * 16);
        #pragma unroll
        for (int n = 0; n < 4; ++n)
            bf[n] = *(const short8*)((char*)Bsm + (wn * 64 + n * 16 + (l & 15)) * 80 + (l >> 4) * 16);

        #pragma unroll
        for (int m = 0; m < 4; ++m)
            #pragma unroll
            for (int n = 0; n < 4; ++n)
                acc[m][n] = __builtin_amdgcn_mfma_f32_16x16x32_bf16(af[m], bf[n], acc[m][n], 0, 0, 0);
    }

    const int lr = (l >> 4) * 4, lc = l & 15;
    #pragma unroll
    for (int m = 0; m < 4; ++m)
        #pragma unroll
        for (int n = 0; n < 4; ++n) {
            int col = bcol + wn * 64 + n * 16 + lc;
            float bsum = bih[col] + bhh[col];
            #pragma unroll
            for (int r = 0; r < 4; ++r) {
                int rowg = brow + wm * 64 + m * 16 + lr + r;
                C[(size_t)rowg * 8192 + col] = acc[m][n][r] + bsum;
            }
        }
}

// ---------------- persistent cooperative LSTM recurrence ------------------------
// R9 structure with ONE change: poll duty concentrated in 2 waves (128 threads,
// 16 slots each via 8 pipelined dwordx4) -> 4x fewer L3 transactions per sweep,
// 384 threads idle at the barrier instead of hammering L3.
//  - hslot[2][2048] u64 {f32 h, u32 tag}, parity double-buffered; step t polls
//    buf[t&1] for tag==t (race-free by the R7 induction).
//  - dot: register-f32 W slice, wave u owns unit hbase+u, pure FMA.
//  - tail: wave 0 lanes 0-7 gates + c update + ONE coalesced swap_x2 publish.
__global__ void __launch_bounds__(512, 1) k_lstm_rec(
    const ushort* __restrict__ Whh,          // bf16 [8192][2048]
    const float* __restrict__ xg,            // [4096][8192]
    unsigned long long* __restrict__ hslot,  // [2][2048] {h,tag}, 0xFF-memset
    const float* __restrict__ Wlin,          // [2048]
    const float* __restrict__ blin,          // [1]
    float* __restrict__ out)                 // [1]
{
    extern __shared__ char smem[];
    float* h_lds = (float*)smem;                // 2304 f32 padded (9216 B)
    float* g_lds = (float*)(smem + 9216);       // 32 gate sums
    float* r_lds = (float*)(smem + 9216 + 128); // 8 f32 final-reduce scratch

    const int tid = threadIdx.x;
    const int b   = blockIdx.x;
    const int hbase = b * 8;
    const int u  = tid >> 6;        // wave id = local hidden unit
    const int g  = (tid >> 4) & 3;  // gate (torch order i,f,g,o)
    const int cc = tid & 15;        // col-chunk

    // one-time: stage + expand this thread's W row slice to f32 registers
    // row = g*2048 + hbase + u, cols cc*8 + k*128 + j (j=0..7, k=0..15)
    f32x4 wf[32];
    {
        const ushort* wr = Whh + (size_t)((g << 11) + hbase + u) * 2048 + (cc << 3);
        #pragma unroll
        for (int k = 0; k < 16; ++k) {
            uint4 wv = *(const uint4*)(wr + (k << 7));
            wf[2 * k]     = (f32x4){bf_lo(wv.x), bf_hi(wv.x), bf_lo(wv.y), bf_hi(wv.y)};
            wf[2 * k + 1] = (f32x4){bf_lo(wv.z), bf_hi(wv.z), bf_lo(wv.w), bf_hi(wv.w)};
        }
    }

    float c_reg = 0.0f;   // lives on wave 0 lanes 0-7 (unit = lane)

    // publish h_0 = 0 with tag 0 into buf[0] (one coalesced wave-instruction)
    if (tid < 8)
        atomic_pub_u64(&hslot[hbase + tid], 0ull);

    for (int t = 0; t < SEQ; ++t) {
        const unsigned long long* src = hslot + (size_t)(t & 1) * HID;
        unsigned long long*       dst = hslot + (size_t)((t + 1) & 1) * HID;

        // wave-0 xg prefetch (independent of h; plain cached loads)
        float xgv0 = 0.f, xgv1 = 0.f, xgv2 = 0.f, xgv3 = 0.f;
        if (tid < 8) {
            const float* xr = xg + (size_t)t * G4 + hbase + tid;
            xgv0 = xr[0]; xgv1 = xr[2048]; xgv2 = xr[4096]; xgv3 = xr[6144];
        }

        // 2 waves poll: thread q (0..127) owns slots 16q..16q+15 of buf[t&1]
        if (tid < 128) {
            const unsigned tgt = (unsigned)t;
            const unsigned long long* pp = src + tid * 16;
            uint32x4 v0, v1, v2, v3, v4, v5, v6, v7;
            int spin = 0;
            while (true) {
                poll16(pp, v0, v1, v2, v3, v4, v5, v6, v7);
                bool ok = (v0.y == tgt) & (v0.w == tgt) & (v1.y == tgt) & (v1.w == tgt)
                        & (v2.y == tgt) & (v2.w == tgt) & (v3.y == tgt) & (v3.w == tgt)
                        & (v4.y == tgt) & (v4.w == tgt) & (v5.y == tgt) & (v5.w == tgt)
                        & (v6.y == tgt) & (v6.w == tgt) & (v7.y == tgt) & (v7.w == tgt);
                if (ok) break;
                if ((++spin & 63) == 0) {
                    // escape hatch (R5-proven, never observed firing)
                    unsigned d = __hip_atomic_load((const unsigned*)src,
                                                   __ATOMIC_ACQUIRE, __HIP_MEMORY_SCOPE_AGENT);
                    asm volatile("" :: "v"(d));
                } else {
                    __builtin_amdgcn_s_sleep(2);
                }
            }
            // stage 16 h values (x/z of each dwordx4) into padded LDS
            float* dptr = h_lds + hmap(tid * 16);
            *(f32x4*)(dptr + 0)  = (f32x4){__uint_as_float(v0.x), __uint_as_float(v0.z),
                                           __uint_as_float(v1.x), __uint_as_float(v1.z)};
            *(f32x4*)(dptr + 4)  = (f32x4){__uint_as_float(v2.x), __uint_as_float(v2.z),
                                           __uint_as_float(v3.x), __uint_as_float(v3.z)};
            *(f32x4*)(dptr + 8)  = (f32x4){__uint_as_float(v4.x), __uint_as_float(v4.z),
                                           __uint_as_float(v5.x), __uint_as_float(v5.z)};
            *(f32x4*)(dptr + 12) = (f32x4){__uint_as_float(v6.x), __uint_as_float(v6.z),
                                           __uint_as_float(v7.x), __uint_as_float(v7.z)};
        }
        __syncthreads();   // [A] h_t staged; all reads of buf[t&1] complete

        // dot: pure f32 FMA, W from registers, h from LDS (4 indep chains)
        float s0 = 0.f, s1 = 0.f, s2 = 0.f, s3 = 0.f;
        #pragma unroll
        for (int k = 0; k < 16; ++k) {
            int col0 = (cc << 3) + (k << 7);
            const float* hp = h_lds + hmap(col0);
            f32x4 ha = *(const f32x4*)hp;
            f32x4 hb = *(const f32x4*)(hp + 4);
            f32x4 wa = wf[2 * k], wb = wf[2 * k + 1];
            s0 += wa.x * ha.x;  s1 += wa.y * ha.y;
            s2 += wa.z * ha.z;  s3 += wa.w * ha.w;
            s0 += wb.x * hb.x;  s1 += wb.y * hb.y;
            s2 += wb.z * hb.z;  s3 += wb.w * hb.w;
        }
        float sum = (s0 + s1) + (s2 + s3);
        // reduce over the 16 cc lanes (intra-wave)
        sum += __shfl_xor(sum, 1);
        sum += __shfl_xor(sum, 2);
        sum += __shfl_xor(sum, 4);
        sum += __shfl_xor(sum, 8);
        if (cc == 0) g_lds[u * 4 + g] = sum;   // W_hh partial (xg added in tail)
        __syncthreads();   // [B] all 32 gate sums visible; LDS reads done

        // wave 0 lanes 0-7: gates, state update, ONE coalesced publish
        if (tid < 8) {
            float gi = fsigmoid(g_lds[tid * 4 + 0] + xgv0);
            float gf = fsigmoid(g_lds[tid * 4 + 1] + xgv1);
            float tg = ftanh   (g_lds[tid * 4 + 2] + xgv2);
            float go = fsigmoid(g_lds[tid * 4 + 3] + xgv3);
            c_reg = gf * c_reg + gi * tg;
            float hn = go * ftanh(c_reg);
            unsigned long long pv =
                ((unsigned long long)(unsigned)(t + 1) << 32) |
                (unsigned long long)__float_as_uint(hn);
            atomic_pub_u64(&dst[hbase + tid], pv);
        }
        // no trailing barrier: pollers only write h_lds after detecting t+1
        // tags, which requires wave0's publish, which follows its g_lds reads
    }

    // final: out = sigmoid(h_SEQ . W_lin + b_lin), block 0 only
    // h_SEQ carries tag SEQ in buf[SEQ&1] = buf[0]
    if (b == 0) {
        const unsigned tgt = (unsigned)SEQ;
        uint32x4 a, bq;
        int spin = 0;
        while (true) {
            load_slot8(hslot + tid * 4, a, bq);
            if (a.y == tgt && a.w == tgt && bq.y == tgt && bq.w == tgt) break;
            if ((++spin & 63) == 0) {
                unsigned d = __hip_atomic_load((const unsigned*)hslot,
                                               __ATOMIC_ACQUIRE, __HIP_MEMORY_SCOPE_AGENT);
                asm volatile("" :: "v"(d));
            } else {
                __builtin_amdgcn_s_sleep(1);
            }
        }
        const float* wl = Wlin + tid * 4;
        float s = __uint_as_float(a.x)  * wl[0] + __uint_as_float(a.z)  * wl[1]
                + __uint_as_float(bq.x) * wl[2] + __uint_as_float(bq.z) * wl[3];
        #pragma unroll
        for (int o = 1; o < 64; o <<= 1) s += __shfl_xor(s, o);
        if ((tid & 63) == 0) r_lds[u] = s;
        __syncthreads();
        if (tid == 0) {
            float tot = r_lds[0] + r_lds[1] + r_lds[2] + r_lds[3]
                      + r_lds[4] + r_lds[5] + r_lds[6] + r_lds[7] + blin[0];
            out[0] = fsigmoid(tot);
        }
    }
}

extern "C" void kernel_launch(void* const* d_in, const int* in_sizes, int n_in,
                              void* d_out, int out_size, void* d_ws, size_t ws_size,
                              hipStream_t stream) {
    const float* x    = (const float*)d_in[0];   // [1][4096][2048]
    const float* Wih  = (const float*)d_in[1];   // [8192][2048]
    const float* Whh  = (const float*)d_in[2];   // [8192][2048]
    const float* bih  = (const float*)d_in[3];   // [8192]
    const float* bhh  = (const float*)d_in[4];   // [8192]
    const float* Wlin = (const float*)d_in[5];   // [1][2048]
    const float* blin = (const float*)d_in[6];   // [1]
    float* out = (float*)d_out;

    char* ws = (char*)d_ws;
    float*              xgbuf = (float*)ws;                        // 134,217,728 B
    ushort*             xbf   = (ushort*)(ws + 134217728);         //  16,777,216 B
    ushort*             wihbf = (ushort*)(ws + 150994944);         //  33,554,432 B
    ushort*             whhbf = (ushort*)(ws + 184549376);         //  33,554,432 B
    unsigned long long* hslot = (unsigned long long*)(ws + 218103808); // 32,768 B

    // f32 -> bf16 (x, W_ih, W_hh)
    k_f32_to_bf16<<<8192,  256, 0, stream>>>(x,   xbf,   2097152);
    k_f32_to_bf16<<<16384, 256, 0, stream>>>(Wih, wihbf, 4194304);
    k_f32_to_bf16<<<16384, 256, 0, stream>>>(Whh, whhbf, 4194304);

    // input GEMM: all timesteps' input-side gate preactivations
    k_gemm_xg<<<dim3(64, 32), 256, 0, stream>>>(xbf, wihbf, bih, bhh, xgbuf);

    // invalidate BOTH parity buffers every call (tags 0..SEQ never match 0xFF)
    hipMemsetAsync(hslot, 0xFF, 2 * HID * sizeof(unsigned long long), stream);

    // persistent cooperative recurrence: proven launch config (dyn LDS + attr)
    hipFuncSetAttribute((const void*)k_lstm_rec,
                        hipFuncAttributeMaxDynamicSharedMemorySize, 163840);
    void* args[] = { (void*)&whhbf, (void*)&xgbuf, (void*)&hslot,
                     (void*)&Wlin, (void*)&blin, (void*)&out };
    hipLaunchCooperativeKernel((const void*)k_lstm_rec, dim3(NBLK), dim3(512),
                               args, 139520, stream);
}

// Round 12
// 12953.883 us; speedup vs baseline: 18.4560x; 1.5633x over previous
//
#include <hip/hip_runtime.h>

typedef __attribute__((ext_vector_type(8))) short short8;
typedef __attribute__((ext_vector_type(4))) float f32x4;
typedef __attribute__((ext_vector_type(4))) unsigned uint32x4;

#define SEQ 4096
#define HID 2048
#define G4  8192
#define NBLK 256

static __device__ __forceinline__ ushort f2bf(float f) {
    unsigned u = __float_as_uint(f);
    u = (u + 0x7fffu + ((u >> 16) & 1u)) >> 16;   // RNE
    return (ushort)u;
}
static __device__ __forceinline__ float bf_lo(unsigned x) { return __uint_as_float(x << 16); }
static __device__ __forceinline__ float bf_hi(unsigned x) { return __uint_as_float(x & 0xffff0000u); }

// Fire-and-forget 32-bit atomic swap publish: 8 lanes, consecutive u32 ->
// ONE wave instruction, one 32 B line at the L3 coherence point.
static __device__ __forceinline__ void atomic_pub_u32(unsigned* p, unsigned v) {
    unsigned long long ap = (unsigned long long)p;
    asm volatile("global_atomic_swap %0, %1, off" :: "v"(ap), "v"(v) : "memory");
}

// 16 B coherent read (sc0 sc1 bypass local caches) + wait: covers 4 packed
// slots in ONE L3 transaction (R9 needed two for the same 4 slots).
static __device__ __forceinline__ uint32x4 load_coh_x4(const void* p) {
    unsigned long long ap = (unsigned long long)p;
    uint32x4 v;
    asm volatile("global_load_dwordx4 %0, %1, off sc0 sc1\n\ts_waitcnt vmcnt(0)"
                 : "=&v"(v) : "v"(ap) : "memory");
    return v;
}

// h_lds address map: +4 floats pad per 32 floats -> reads <=2-way bank aliased
static __device__ __forceinline__ int hmap(int col) { return col + ((col >> 5) << 2); }

static __device__ __forceinline__ float fsigmoid(float x) {
    return 1.0f / (1.0f + __expf(-x));
}
static __device__ __forceinline__ float ftanh(float x) {
    return 1.0f - 2.0f / (__expf(2.0f * x) + 1.0f);
}

// ---------------- f32 -> bf16 conversion (vectorized, 4 elems/thread) ----------
__global__ void __launch_bounds__(256) k_f32_to_bf16(const float* __restrict__ in,
                                                     ushort* __restrict__ out, int n4) {
    int i = blockIdx.x * blockDim.x + threadIdx.x;
    if (i < n4) {
        float4 v = ((const float4*)in)[i];
        ushort4 o;
        o.x = f2bf(v.x); o.y = f2bf(v.y); o.z = f2bf(v.z); o.w = f2bf(v.w);
        ((ushort4*)out)[i] = o;
    }
}

// ---------------- xg = x @ W_ih^T + (b_ih + b_hh), bf16 MFMA, 128x128 tile ------
__global__ void __launch_bounds__(256) k_gemm_xg(
    const ushort* __restrict__ A, const ushort* __restrict__ B,
    const float* __restrict__ bih, const float* __restrict__ bhh,
    float* __restrict__ C)
{
    __shared__ ushort Asm[128 * 40];
    __shared__ ushort Bsm[128 * 40];
    const int tid = threadIdx.x;
    const int brow = blockIdx.y * 128;
    const int bcol = blockIdx.x * 128;
    const int w = tid >> 6, l = tid & 63;
    const int wm = w >> 1, wn = w & 1;

    f32x4 acc[4][4] = {};

    for (int k0 = 0; k0 < 2048; k0 += 32) {
        __syncthreads();
        #pragma unroll
        for (int i = 0; i < 2; ++i) {
            int q = tid + i * 256;
            int r = q >> 2, kc = q & 3;
            *(uint4*)((char*)Asm + r * 80 + kc * 16) =
                *(const uint4*)(A + (size_t)(brow + r) * 2048 + k0 + kc * 8);
            *(uint4*)((char*)Bsm + r * 80 + kc * 16) =
                *(const uint4*)(B + (size_t)(bcol + r) * 2048 + k0 + kc * 8);
        }
        __syncthreads();

        short8 af[4], bf[4];
        #pragma unroll
        for (int m = 0; m < 4; ++m)
            af[m] = *(const short8*)((char*)Asm + (wm * 64 + m * 16 + (l & 15)) * 80 + (l >> 4) * 16);
        #pragma unroll
        for (int n = 0; n < 4; ++n)
            bf[n] = *(const short8*)((char*)Bsm + (wn * 64 + n * 16 + (l & 15)) * 80 + (l >> 4) * 16);

        #pragma unroll
        for (int m = 0; m < 4; ++m)
            #pragma unroll
            for (int n = 0; n < 4; ++n)
                acc[m][n] = __builtin_amdgcn_mfma_f32_16x16x32_bf16(af[m], bf[n], acc[m][n], 0, 0, 0);
    }

    const int lr = (l >> 4) * 4, lc = l & 15;
    #pragma unroll
    for (int m = 0; m < 4; ++m)
        #pragma unroll
        for (int n = 0; n < 4; ++n) {
            int col = bcol + wn * 64 + n * 16 + lc;
            float bsum = bih[col] + bhh[col];
            #pragma unroll
            for (int r = 0; r < 4; ++r) {
                int rowg = brow + wm * 64 + m * 16 + lr + r;
                C[(size_t)rowg * 8192 + col] = acc[m][n][r] + bsum;
            }
        }
}

// ---------------- persistent cooperative LSTM recurrence ------------------------
// R9 structure with ONE change: slots packed to u32 {bf16 h | tag16} ->
// one dwordx4 poll covers 4 slots (512 tx/block-sweep vs R9's 1024).
//  - hslot[2][2048] u32, parity double-buffered; step t polls buf[t&1] for
//    tag16 == t&0xFFFF (race-free by the R7 induction; SEQ<65536 no wrap;
//    0xFF-memset tag=0xFFFF never matches a real step).
//  - dot: register-f32 W slice, wave u owns unit hbase+u, pure FMA.
//  - tail: wave 0 lanes 0-7 gates + c update + ONE coalesced 32b-swap publish.
__global__ void __launch_bounds__(512, 1) k_lstm_rec(
    const ushort* __restrict__ Whh,   // bf16 [8192][2048]
    const float* __restrict__ xg,     // [4096][8192]
    unsigned* __restrict__ hslot,     // [2][2048] {bf16 h | tag16}, 0xFF-memset
    const float* __restrict__ Wlin,   // [2048]
    const float* __restrict__ blin,   // [1]
    float* __restrict__ out)          // [1]
{
    extern __shared__ char smem[];
    float* h_lds = (float*)smem;                // 2304 f32 padded (9216 B)
    float* g_lds = (float*)(smem + 9216);       // 32 gate sums
    float* r_lds = (float*)(smem + 9216 + 128); // 8 f32 final-reduce scratch

    const int tid = threadIdx.x;
    const int b   = blockIdx.x;
    const int hbase = b * 8;
    const int u  = tid >> 6;        // wave id = local hidden unit
    const int g  = (tid >> 4) & 3;  // gate (torch order i,f,g,o)
    const int cc = tid & 15;        // col-chunk

    // one-time: stage + expand this thread's W row slice to f32 registers
    // row = g*2048 + hbase + u, cols cc*8 + k*128 + j (j=0..7, k=0..15)
    f32x4 wf[32];
    {
        const ushort* wr = Whh + (size_t)((g << 11) + hbase + u) * 2048 + (cc << 3);
        #pragma unroll
        for (int k = 0; k < 16; ++k) {
            uint4 wv = *(const uint4*)(wr + (k << 7));
            wf[2 * k]     = (f32x4){bf_lo(wv.x), bf_hi(wv.x), bf_lo(wv.y), bf_hi(wv.y)};
            wf[2 * k + 1] = (f32x4){bf_lo(wv.z), bf_hi(wv.z), bf_lo(wv.w), bf_hi(wv.w)};
        }
    }

    float c_reg = 0.0f;   // lives on wave 0 lanes 0-7 (unit = lane)

    // publish h_0 = 0 with tag 0 into buf[0]: slot = 0x00000000
    if (tid < 8)
        atomic_pub_u32(&hslot[hbase + tid], 0u);

    for (int t = 0; t < SEQ; ++t) {
        const unsigned* src = hslot + (size_t)(t & 1) * HID;
        unsigned*       dst = hslot + (size_t)((t + 1) & 1) * HID;

        // wave-0 xg prefetch (independent of h; plain cached loads)
        float xgv0 = 0.f, xgv1 = 0.f, xgv2 = 0.f, xgv3 = 0.f;
        if (tid < 8) {
            const float* xr = xg + (size_t)t * G4 + hbase + tid;
            xgv0 = xr[0]; xgv1 = xr[2048]; xgv2 = xr[4096]; xgv3 = xr[6144];
        }

        // poll own 4 packed slots of buf[t&1] with ONE dwordx4 until tags == t
        {
            const unsigned tgt = (unsigned)t & 0xFFFFu;
            uint32x4 d;
            int spin = 0;
            while (true) {
                d = load_coh_x4(src + tid * 4);
                if ((d.x & 0xFFFFu) == tgt && (d.y & 0xFFFFu) == tgt &&
                    (d.z & 0xFFFFu) == tgt && (d.w & 0xFFFFu) == tgt) break;
                if ((++spin & 63) == 0) {
                    // escape hatch (R5-proven, never observed firing)
                    unsigned e = __hip_atomic_load(src, __ATOMIC_ACQUIRE,
                                                   __HIP_MEMORY_SCOPE_AGENT);
                    asm volatile("" :: "v"(e));
                } else {
                    __builtin_amdgcn_s_sleep(1);
                }
            }
            *(f32x4*)(h_lds + hmap(tid * 4)) =
                (f32x4){bf_hi(d.x), bf_hi(d.y), bf_hi(d.z), bf_hi(d.w)};
        }
        __syncthreads();   // [A] h_t staged; all reads of buf[t&1] complete

        // dot: pure f32 FMA, W from registers, h from LDS (4 indep chains)
        float s0 = 0.f, s1 = 0.f, s2 = 0.f, s3 = 0.f;
        #pragma unroll
        for (int k = 0; k < 16; ++k) {
            int col0 = (cc << 3) + (k << 7);
            const float* hp = h_lds + hmap(col0);
            f32x4 ha = *(const f32x4*)hp;
            f32x4 hb = *(const f32x4*)(hp + 4);
            f32x4 wa = wf[2 * k], wb = wf[2 * k + 1];
            s0 += wa.x * ha.x;  s1 += wa.y * ha.y;
            s2 += wa.z * ha.z;  s3 += wa.w * ha.w;
            s0 += wb.x * hb.x;  s1 += wb.y * hb.y;
            s2 += wb.z * hb.z;  s3 += wb.w * hb.w;
        }
        float sum = (s0 + s1) + (s2 + s3);
        // reduce over the 16 cc lanes (intra-wave)
        sum += __shfl_xor(sum, 1);
        sum += __shfl_xor(sum, 2);
        sum += __shfl_xor(sum, 4);
        sum += __shfl_xor(sum, 8);
        if (cc == 0) g_lds[u * 4 + g] = sum;   // W_hh partial (xg added in tail)
        __syncthreads();   // [B] all 32 gate sums visible; LDS reads done

        // wave 0 lanes 0-7: gates, state update, ONE coalesced publish
        if (tid < 8) {
            float gi = fsigmoid(g_lds[tid * 4 + 0] + xgv0);
            float gf = fsigmoid(g_lds[tid * 4 + 1] + xgv1);
            float tg = ftanh   (g_lds[tid * 4 + 2] + xgv2);
            float go = fsigmoid(g_lds[tid * 4 + 3] + xgv3);
            c_reg = gf * c_reg + gi * tg;
            float hn = go * ftanh(c_reg);
            unsigned pv = ((unsigned)f2bf(hn) << 16) | ((unsigned)(t + 1) & 0xFFFFu);
            atomic_pub_u32(&dst[hbase + tid], pv);
        }
        // no trailing barrier: staging for t+1 requires detecting tags t+1,
        // which requires wave0's publish, which follows its g_lds reads
    }

    // final: out = sigmoid(h_SEQ . W_lin + b_lin), block 0 only
    // h_SEQ carries tag 4096 in buf[SEQ&1] = buf[0]
    if (b == 0) {
        const unsigned tgt = (unsigned)SEQ & 0xFFFFu;
        uint32x4 d;
        int spin = 0;
        while (true) {
            d = load_coh_x4(hslot + tid * 4);
            if ((d.x & 0xFFFFu) == tgt && (d.y & 0xFFFFu) == tgt &&
                (d.z & 0xFFFFu) == tgt && (d.w & 0xFFFFu) == tgt) break;
            if ((++spin & 63) == 0) {
                unsigned e = __hip_atomic_load(hslot, __ATOMIC_ACQUIRE,
                                               __HIP_MEMORY_SCOPE_AGENT);
                asm volatile("" :: "v"(e));
            } else {
                __builtin_amdgcn_s_sleep(1);
            }
        }
        const float* wl = Wlin + tid * 4;
        float s = bf_hi(d.x) * wl[0] + bf_hi(d.y) * wl[1]
                + bf_hi(d.z) * wl[2] + bf_hi(d.w) * wl[3];
        #pragma unroll
        for (int o = 1; o < 64; o <<= 1) s += __shfl_xor(s, o);
        if ((tid & 63) == 0) r_lds[u] = s;
        __syncthreads();
        if (tid == 0) {
            float tot = r_lds[0] + r_lds[1] + r_lds[2] + r_lds[3]
                      + r_lds[4] + r_lds[5] + r_lds[6] + r_lds[7] + blin[0];
            out[0] = fsigmoid(tot);
        }
    }
}

extern "C" void kernel_launch(void* const* d_in, const int* in_sizes, int n_in,
                              void* d_out, int out_size, void* d_ws, size_t ws_size,
                              hipStream_t stream) {
    const float* x    = (const float*)d_in[0];   // [1][4096][2048]
    const float* Wih  = (const float*)d_in[1];   // [8192][2048]
    const float* Whh  = (const float*)d_in[2];   // [8192][2048]
    const float* bih  = (const float*)d_in[3];   // [8192]
    const float* bhh  = (const float*)d_in[4];   // [8192]
    const float* Wlin = (const float*)d_in[5];   // [1][2048]
    const float* blin = (const float*)d_in[6];   // [1]
    float* out = (float*)d_out;

    char* ws = (char*)d_ws;
    float*    xgbuf = (float*)ws;                         // 134,217,728 B
    ushort*   xbf   = (ushort*)(ws + 134217728);          //  16,777,216 B
    ushort*   wihbf = (ushort*)(ws + 150994944);          //  33,554,432 B
    ushort*   whhbf = (ushort*)(ws + 184549376);          //  33,554,432 B
    unsigned* hslot = (unsigned*)(ws + 218103808);        //      16,384 B (2x2048 u32)

    // f32 -> bf16 (x, W_ih, W_hh)
    k_f32_to_bf16<<<8192,  256, 0, stream>>>(x,   xbf,   2097152);
    k_f32_to_bf16<<<16384, 256, 0, stream>>>(Wih, wihbf, 4194304);
    k_f32_to_bf16<<<16384, 256, 0, stream>>>(Whh, whhbf, 4194304);

    // input GEMM: all timesteps' input-side gate preactivations
    k_gemm_xg<<<dim3(64, 32), 256, 0, stream>>>(xbf, wihbf, bih, bhh, xgbuf);

    // invalidate BOTH parity buffers every call (tag 0xFFFF never matches)
    hipMemsetAsync(hslot, 0xFF, 2 * HID * sizeof(unsigned), stream);

    // persistent cooperative recurrence: proven launch config (dyn LDS + attr)
    hipFuncSetAttribute((const void*)k_lstm_rec,
                        hipFuncAttributeMaxDynamicSharedMemorySize, 163840);
    void* args[] = { (void*)&whhbf, (void*)&xgbuf, (void*)&hslot,
                     (void*)&Wlin, (void*)&blin, (void*)&out };
    hipLaunchCooperativeKernel((const void*)k_lstm_rec, dim3(NBLK), dim3(512),
                               args, 139520, stream);
}